// Round 3
// baseline (399.910 us; speedup 1.0000x reference)
//
#include <hip/hip_runtime.h>

// B=8, N=256, D=128
// out[b,i,d] = sum_e T[b,i,e]*W[e,d] + bias[d]
//   T[b,i,e]  = sum_j adj[b,i,j]*dep[b,j,i,e]  +  (adj[b] @ hidden[b])[i,e]
//
// K1: pure adj-weighted dep reduction (split-K over j), register a-values,
//     fully-unrolled j-loop -> 32 independent float4 loads/thread, no LDS in
//     the stream loop. 2048 blocks (8/CU). Writes P[b,i,ch,e] (16.8 MB) to ws.
// K2: chunk-reduce + adj@hidden matvec (L2-hot) + 128x128 W matvec + bias.

constexpr int Bc  = 8;
constexpr int Nc  = 256;
constexpr int Dc  = 128;
constexpr int JC  = 16;          // j per chunk
constexpr int NCH = Nc / JC;     // 16
constexpr int IT  = 16;          // i per block
constexpr int NIQ = Nc / IT;     // 16

__global__ __launch_bounds__(256, 4) void depgcn_k1(
    const float* __restrict__ adj,     // [B,N,N]
    const float* __restrict__ dep,     // [B,N,N,D]
    float* __restrict__ P)             // [B,N,NCH,D]
{
    const int blk = blockIdx.x;        // 0..2047 ; iq fastest
    const int iq  = blk & (NIQ - 1);
    const int jc  = (blk >> 4) & (NCH - 1);
    const int b   = blk >> 8;
    const int t   = threadIdx.x;
    const int g   = t >> 5;            // 0..7 ; owns i_local g and g+8
    const int c   = t & 31;            // e = 4c..4c+3

    __shared__ float sA[IT][JC];       // 1 KB

    {   // stage adj tile: sA[iL][jL] = adj[b, iq*IT+iL, jc*JC+jL]
        const int iL = t >> 4, jL = t & 15;
        sA[iL][jL] = adj[((size_t)b * Nc + iq * IT + iL) * Nc + jc * JC + jL];
    }
    __syncthreads();

    // preload this thread's 32 a-values into registers (broadcast LDS reads)
    float a0[JC], a1[JC];
    #pragma unroll
    for (int j = 0; j < JC; ++j) { a0[j] = sA[g][j]; a1[j] = sA[g + 8][j]; }

    const float* depB = dep + (((size_t)b * Nc + jc * JC) * Nc + iq * IT) * Dc
                            + (size_t)c * 4;

    float4 acc0 = make_float4(0.f, 0.f, 0.f, 0.f);
    float4 acc1 = make_float4(0.f, 0.f, 0.f, 0.f);

    #pragma unroll
    for (int j = 0; j < JC; ++j) {
        const float* dj = depB + (size_t)j * Nc * Dc;
        const float4 d0 = *(const float4*)(dj + (size_t)g * Dc);
        const float4 d1 = *(const float4*)(dj + (size_t)(g + 8) * Dc);
        acc0.x = fmaf(a0[j], d0.x, acc0.x);
        acc0.y = fmaf(a0[j], d0.y, acc0.y);
        acc0.z = fmaf(a0[j], d0.z, acc0.z);
        acc0.w = fmaf(a0[j], d0.w, acc0.w);
        acc1.x = fmaf(a1[j], d1.x, acc1.x);
        acc1.y = fmaf(a1[j], d1.y, acc1.y);
        acc1.z = fmaf(a1[j], d1.z, acc1.z);
        acc1.w = fmaf(a1[j], d1.w, acc1.w);
    }

    {
        const int ig0 = iq * IT + g;
        const int ig1 = ig0 + 8;
        float* p0 = P + (((size_t)b * Nc + ig0) * NCH + jc) * Dc + (size_t)c * 4;
        float* p1 = P + (((size_t)b * Nc + ig1) * NCH + jc) * Dc + (size_t)c * 4;
        *(float4*)p0 = acc0;
        *(float4*)p1 = acc1;
    }
}

__global__ __launch_bounds__(256) void depgcn_k2(
    const float* __restrict__ P,       // [B,N,NCH,D]
    const float* __restrict__ hidden,  // [B,N,D]
    const float* __restrict__ adj,     // [B,N,N]
    const float* __restrict__ W,       // [D,D]
    const float* __restrict__ bias,    // [D]
    float* __restrict__ out)           // [B,N,D]
{
    const int bi = blockIdx.x;
    const int b  = bi >> 8;
    const int i  = bi & (Nc - 1);
    const int t  = threadIdx.x;
    const int e  = t & (Dc - 1);
    const int h  = t >> 7;             // 0 or 1

    __shared__ float sAdj[Nc];
    __shared__ float sTp[2][Dc];
    __shared__ float sO[2][Dc];

    sAdj[t] = adj[((size_t)b * Nc + i) * Nc + t];
    __syncthreads();

    // half-split: chunk-reduce of P + adj@hidden matvec
    {
        float s = 0.f;
        const float* pp = P + (((size_t)b * Nc + i) * NCH + h * 8) * Dc + e;
        #pragma unroll
        for (int ch = 0; ch < 8; ++ch) s += pp[(size_t)ch * Dc];

        const float* hp = hidden + ((size_t)b * Nc + h * 128) * Dc + e;
        #pragma unroll 8
        for (int jj = 0; jj < 128; ++jj)
            s = fmaf(sAdj[h * 128 + jj], hp[(size_t)jj * Dc], s);
        sTp[h][e] = s;
    }
    __syncthreads();

    // out[b,i,d] = sum_e T[e]*W[e,d] + bias[d]; e-range split across halves
    {
        const float* wp = W + (size_t)(h * 64) * Dc + e;
        float s = 0.f;
        #pragma unroll 8
        for (int q = 0; q < 64; ++q) {
            const float te = sTp[0][h * 64 + q] + sTp[1][h * 64 + q];
            s = fmaf(te, wp[(size_t)q * Dc], s);
        }
        sO[h][e] = s;
    }
    __syncthreads();

    if (t < Dc)
        out[((size_t)b * Nc + i) * Dc + t] = sO[0][t] + sO[1][t] + bias[t];
}

extern "C" void kernel_launch(void* const* d_in, const int* in_sizes, int n_in,
                              void* d_out, int out_size, void* d_ws, size_t ws_size,
                              hipStream_t stream) {
    const float* hidden = (const float*)d_in[0];
    const float* adj    = (const float*)d_in[1];
    const float* dep    = (const float*)d_in[2];
    const float* W      = (const float*)d_in[3];
    const float* bias   = (const float*)d_in[4];
    float* out          = (float*)d_out;
    float* P            = (float*)d_ws;   // B*N*NCH*D*4 = 16.8 MB

    depgcn_k1<<<dim3(Bc * NCH * NIQ), dim3(256), 0, stream>>>(adj, dep, P);
    depgcn_k2<<<dim3(Bc * Nc), dim3(256), 0, stream>>>(P, hidden, adj, W, bias, out);
}

// Round 5
// 354.920 us; speedup vs baseline: 1.1268x; 1.1268x over previous
//
#include <hip/hip_runtime.h>

// B=8, N=256, D=128
// out[b,i,d] = sum_e T[b,i,e]*W[e,d] + bias[d]
//   T[b,i,e]  = sum_j adj[b,i,j] * (hidden[b,j,e] + dep[b,j,i,e])
//
// Single kernel, one block per (b,i): no workspace traffic, one dispatch.
// The timed replay carries ~1.6 GB of harness fill/restore traffic, so our
// controllable slice is the 268 MB dep read; goal = stream it at max BW.
//  - group g (32 lanes) owns contiguous j-range [g*32, g*32+32): sequential
//    128 KB-page walk per group (DRAM-friendly), full 512 B row per load.
//  - 4-deep unroll: 4 independent nontemporal float4 loads in flight.
//  - dep is read exactly once grid-wide -> nontemporal (don't fight the
//    harness's dirty-line drain for L2/L3 space). hidden/adj stay cached.

constexpr int Bc = 8;
constexpr int Nc = 256;
constexpr int Dc = 128;

typedef float floatx4 __attribute__((ext_vector_type(4)));  // native vec for NT builtin

__global__ __launch_bounds__(256, 2) void depgcn_kernel(
    const float* __restrict__ hidden,  // [B,N,D]
    const float* __restrict__ adj,     // [B,N,N]
    const float* __restrict__ dep,     // [B,N,N,D]
    const float* __restrict__ W,       // [D,D]
    const float* __restrict__ bias,    // [D]
    float* __restrict__ out)           // [B,N,D]
{
    const int bi = blockIdx.x;        // 0 .. B*N-1
    const int b  = bi >> 8;
    const int i  = bi & (Nc - 1);
    const int t  = threadIdx.x;       // 0..255
    const int g  = t >> 5;            // j-range owner 0..7
    const int c  = t & 31;            // e = 4c..4c+3

    __shared__ float sAdj[Nc];
    __shared__ float sP[8][Dc];       // per-group partial T
    __shared__ float sT[Dc];
    __shared__ float sO[2][Dc];

    sAdj[t] = adj[((size_t)b * Nc + i) * Nc + t];
    __syncthreads();

    // dep[b, j, i, 4c]; j-stride = N*D floats (128 KB)
    const float* depP = dep + (((size_t)b * Nc) * Nc + i) * Dc + (size_t)c * 4
                            + (size_t)(g * 32) * Nc * Dc;
    const float* hidP = hidden + ((size_t)b * Nc + g * 32) * Dc + (size_t)c * 4;

    floatx4 acc = {0.f, 0.f, 0.f, 0.f};

    #pragma unroll
    for (int jj = 0; jj < 32; jj += 4) {
        // 4 independent NT loads in flight
        const floatx4 d0 = __builtin_nontemporal_load(
            (const floatx4*)(depP + (size_t)(jj + 0) * Nc * Dc));
        const floatx4 d1 = __builtin_nontemporal_load(
            (const floatx4*)(depP + (size_t)(jj + 1) * Nc * Dc));
        const floatx4 d2 = __builtin_nontemporal_load(
            (const floatx4*)(depP + (size_t)(jj + 2) * Nc * Dc));
        const floatx4 d3 = __builtin_nontemporal_load(
            (const floatx4*)(depP + (size_t)(jj + 3) * Nc * Dc));
        const floatx4 h0 = *(const floatx4*)(hidP + (size_t)(jj + 0) * Dc);
        const floatx4 h1 = *(const floatx4*)(hidP + (size_t)(jj + 1) * Dc);
        const floatx4 h2 = *(const floatx4*)(hidP + (size_t)(jj + 2) * Dc);
        const floatx4 h3 = *(const floatx4*)(hidP + (size_t)(jj + 3) * Dc);
        const float a0 = sAdj[g * 32 + jj + 0];
        const float a1 = sAdj[g * 32 + jj + 1];
        const float a2 = sAdj[g * 32 + jj + 2];
        const float a3 = sAdj[g * 32 + jj + 3];
        acc += a0 * (d0 + h0);
        acc += a1 * (d1 + h1);
        acc += a2 * (d2 + h2);
        acc += a3 * (d3 + h3);
    }
    *(floatx4*)&sP[g][c * 4] = acc;
    __syncthreads();

    // reduce 8 group-partials -> T[b,i,:]
    if (t < Dc) {
        float s = 0.f;
        #pragma unroll
        for (int gg = 0; gg < 8; ++gg) s += sP[gg][t];
        sT[t] = s;
    }
    __syncthreads();

    // out[b,i,d] = sum_e sT[e]*W[e,d] + bias[d]; e-range split over 2 halves
    {
        const int d = t & (Dc - 1);
        const int h = t >> 7;
        const float* wp = W + (size_t)(h * 64) * Dc + d;
        float s = 0.f;
        #pragma unroll 8
        for (int e = 0; e < 64; ++e)
            s = fmaf(sT[h * 64 + e], wp[(size_t)e * Dc], s);
        sO[h][d] = s;
    }
    __syncthreads();

    if (t < Dc)
        out[((size_t)b * Nc + i) * Dc + t] = sO[0][t] + sO[1][t] + bias[t];
}

extern "C" void kernel_launch(void* const* d_in, const int* in_sizes, int n_in,
                              void* d_out, int out_size, void* d_ws, size_t ws_size,
                              hipStream_t stream) {
    const float* hidden = (const float*)d_in[0];
    const float* adj    = (const float*)d_in[1];
    const float* dep    = (const float*)d_in[2];
    const float* W      = (const float*)d_in[3];
    const float* bias   = (const float*)d_in[4];
    float* out          = (float*)d_out;

    depgcn_kernel<<<dim3(Bc * Nc), dim3(256), 0, stream>>>(hidden, adj, dep, W, bias, out);
}